// Round 2
// baseline (386.291 us; speedup 1.0000x reference)
//
#include <hip/hip_runtime.h>
#include <hip/hip_bf16.h>

// (B,T,D,H) = (4,2048,384,6), HD=64. Inputs/output f32; intermediates bf16.
#define BB   4
#define TT   2048
#define DDIM 384
#define HH   6
#define HD   64
#define BT   (BB*TT)
#define QKVC (3*DDIM)

#define QSCALE 0.18033688011112042f   // 0.125 * log2(e), folded into Q at RoPE
#define LOG2E  1.4426950408889634f

typedef __attribute__((ext_vector_type(8))) short short8v;
typedef __attribute__((ext_vector_type(4))) float float4v;
typedef unsigned short u16;

static __device__ __forceinline__ u16 f2bu(float f) {
    __hip_bfloat16 h = __float2bfloat16(f);
    return __builtin_bit_cast(u16, h);
}
static __device__ __forceinline__ unsigned pk2(float lo, float hi) {
    return (unsigned)f2bu(lo) | ((unsigned)f2bu(hi) << 16);   // -> v_cvt_pk_bf16_f32
}
static __device__ __forceinline__ short8v frag4(uint4 v) {
    return __builtin_bit_cast(short8v, v);
}
// permlane swaps (gfx950):
//  p32: a=[a_lo, b_lo], b=[a_hi, b_hi]; p16: per-32 rows interleave 16-groups
static __device__ __forceinline__ void pl32swap(unsigned &a, unsigned &b) {
    auto r = __builtin_amdgcn_permlane32_swap(a, b, false, false);
    a = r[0]; b = r[1];
}
static __device__ __forceinline__ void pl16swap(unsigned &a, unsigned &b) {
    auto r = __builtin_amdgcn_permlane16_swap(a, b, false, false);
    a = r[0]; b = r[1];
}

#define MFMA16(a, b, c) __builtin_amdgcn_mfma_f32_16x16x32_bf16((a), (b), (c), 0, 0, 0)

// ---------------------------------------------------------------------------
// K0 (merged prep): blocks [0,108): wqkv^T ; [108,144): wproj^T ; [144,912):
// x -> bf16 cast.  (unchanged)
// ---------------------------------------------------------------------------
__global__ __launch_bounds__(256) void prep_kernel(
    const float* __restrict__ wqkv, const float* __restrict__ wproj,
    const float* __restrict__ x,
    u16* __restrict__ wqkvT, u16* __restrict__ wprojT, u16* __restrict__ xb)
{
    const int bid = blockIdx.x;
    const int t = threadIdx.x;
    if (bid >= 144) {
        size_t base = (size_t)(bid - 144) * 4096 + (size_t)t * 16;
        const float* gp = x + base;
        __align__(16) u16 tmp[16];
        #pragma unroll
        for (int u = 0; u < 4; ++u) {
            float4 v = *(const float4*)(gp + 4 * u);
            tmp[4 * u + 0] = f2bu(v.x); tmp[4 * u + 1] = f2bu(v.y);
            tmp[4 * u + 2] = f2bu(v.z); tmp[4 * u + 3] = f2bu(v.w);
        }
        *(uint4*)(xb + base)     = *(const uint4*)tmp;
        *(uint4*)(xb + base + 8) = *(const uint4*)(tmp + 8);
        return;
    }
    const float* in; u16* out; int K, C, c0, k0;
    if (bid < 108) { in = wqkv;  out = wqkvT;  K = DDIM; C = QKVC;
                     c0 = (bid % 18) * 64; k0 = (bid / 18) * 64; }
    else           { int b2 = bid - 108; in = wproj; out = wprojT; K = DDIM; C = DDIM;
                     c0 = (b2 % 6) * 64; k0 = (b2 / 6) * 64; }
    __shared__ float tr[64][65];
    {
        int kr = t >> 2, cb = (t & 3) * 16;
        const float* gp = in + (size_t)(k0 + kr) * C + c0 + cb;
        #pragma unroll
        for (int u = 0; u < 4; ++u) {
            float4 v = *(const float4*)(gp + 4 * u);
            tr[cb + 4 * u + 0][kr] = v.x;
            tr[cb + 4 * u + 1][kr] = v.y;
            tr[cb + 4 * u + 2][kr] = v.z;
            tr[cb + 4 * u + 3][kr] = v.w;
        }
    }
    __syncthreads();
    {
        int c = t >> 2, kb = (t & 3) * 16;
        __align__(16) u16 tmp[16];
        #pragma unroll
        for (int u = 0; u < 16; ++u) tmp[u] = f2bu(tr[c][kb + u]);
        u16* op = out + (size_t)(c0 + c) * K + k0 + kb;
        *(uint4*)op       = *(const uint4*)tmp;
        *(uint4*)(op + 8) = *(const uint4*)(tmp + 8);
    }
}

// ---------------------------------------------------------------------------
// K1: qkv = xb @ wqkvT, RoPE fused in epilogue. Direct-fragment GEMM:
// no LDS, no syncthreads; raw s_barrier per K-step keeps the 4 waves
// lockstepped so their identical B-frag loads dedup in L1.
// Q is pre-scaled by 0.125*log2(e) so attn softmax is exp2(fma(b,log2e,s)).
//   q,k -> [bh][t][d] bf16 ; v -> TRANSPOSED [bh][d][t] bf16.
// ---------------------------------------------------------------------------
__global__ __launch_bounds__(256) void qkv_rope_kernel(
    const u16* __restrict__ xb, const u16* __restrict__ wt,
    const float* __restrict__ cs, const float* __restrict__ sn,
    u16* __restrict__ qb, u16* __restrict__ kb, u16* __restrict__ vtb)
{
    const int t = threadIdx.x;
    const int wv = t >> 6, lane = t & 63, quad = lane >> 4, lo = lane & 15;
    const int r0 = blockIdx.y * 64, c0 = blockIdx.x * 64;

    const u16* abase = xb + (size_t)(r0 + 16 * wv + lo) * DDIM + quad * 8;
    const u16* bbase = wt + (size_t)(c0 + lo) * DDIM + quad * 8;

    uint4 af[2], bf[4][2];
    af[0] = *(const uint4*)(abase);
    af[1] = *(const uint4*)(abase + 32);
    #pragma unroll
    for (int nt = 0; nt < 4; ++nt) {
        bf[nt][0] = *(const uint4*)(bbase + nt * 16 * DDIM);
        bf[nt][1] = *(const uint4*)(bbase + nt * 16 * DDIM + 32);
    }

    float4v acc[4] = {};
    for (int kk = 0; kk < 6; ++kk) {
        __builtin_amdgcn_s_barrier();
        const int kn = (kk < 5 ? kk + 1 : 5) * 64;
        short8v a0 = frag4(af[0]), a1 = frag4(af[1]);
        #pragma unroll
        for (int nt = 0; nt < 4; ++nt) {
            acc[nt] = MFMA16(a0, frag4(bf[nt][0]), acc[nt]);
            acc[nt] = MFMA16(a1, frag4(bf[nt][1]), acc[nt]);
        }
        af[0] = *(const uint4*)(abase + kn);
        af[1] = *(const uint4*)(abase + kn + 32);
        #pragma unroll
        for (int nt = 0; nt < 4; ++nt) {
            bf[nt][0] = *(const uint4*)(bbase + nt * 16 * DDIM + kn);
            bf[nt][1] = *(const uint4*)(bbase + nt * 16 * DDIM + kn + 32);
        }
    }

    const int sec = blockIdx.x / 6;     // 0=q, 1=k, 2=v
    const int h   = blockIdx.x % 6;
    const int rbase = r0 + 16 * wv + 4 * quad;
    const int bidx  = r0 >> 11;
    const int tbase = rbase & (TT - 1);

    if (sec == 2) {
        #pragma unroll
        for (int nt = 0; nt < 4; ++nt) {
            int d = nt * 16 + lo;
            unsigned a0 = pk2(acc[nt][0], acc[nt][1]);
            unsigned a1 = pk2(acc[nt][2], acc[nt][3]);
            u16* gp = vtb + ((size_t)(bidx * HH + h) * HD + d) * TT + tbase;
            *(uint2*)gp = make_uint2(a0, a1);
        }
    } else {
        u16* dst = (sec == 0) ? qb : kb;
        const float scl = (sec == 0) ? QSCALE : 1.0f;
        #pragma unroll
        for (int np = 0; np < 2; ++np) {
            #pragma unroll
            for (int r = 0; r < 4; ++r) {
                int tpos = tbase + r;
                int ci = np * 16 + lo;
                float cv = cs[tpos * 32 + ci];
                float sv = sn[tpos * 32 + ci];
                float x1 = acc[np][r], x2 = acc[np + 2][r];
                u16* gp = dst + ((size_t)(bidx * HH + h) * TT + tpos) * HD;
                gp[ci]      = f2bu((x1 * cv - x2 * sv) * scl);
                gp[ci + 32] = f2bu((x2 * cv + x1 * sv) * scl);
            }
        }
    }
}

// ---------------------------------------------------------------------------
// K2: flash attention, S^T formulation, ZERO LDS:
//  - K/V/bias fragments loaded straight from global (L2-resident per bh via
//    bh%8 XCD pinning; identical addresses across the 4 waves dedup in L1;
//    one raw s_barrier/iter keeps waves lockstepped, no waitcnt drain).
//  - P C-layout -> A-layout in-register: cvt_pk_bf16 + permlane32/16_swap.
//  - exp path: Q carries 0.125*log2e, so p = exp2(fma(bias, log2e, s)).
//  - frags single-buffered, reloaded immediately after last use (~1-iter
//    prefetch distance under compiler-counted vmcnt).
// ---------------------------------------------------------------------------
__global__ __launch_bounds__(256) void attn_kernel(
    const u16* __restrict__ qb, const u16* __restrict__ kb, const u16* __restrict__ vtb,
    const float* __restrict__ bias, u16* __restrict__ ob)
{
    const int t = threadIdx.x;
    const int wv = t >> 6, lane = t & 63, quad = lane >> 4, lo = lane & 15;
    const int bh = blockIdx.x;                    // bh fastest: XCD = bh % 8
    const int b = bh / HH, h = bh % HH;
    const int q0 = blockIdx.y * 64;
    const int qrow = q0 + 16 * wv + lo;           // q-row owned by this lane

    // Q fragments (B-operand of S^T)
    const u16* qbase = qb + ((size_t)bh * TT + qrow) * HD + quad * 8;
    short8v aq0 = frag4(*(const uint4*)qbase);
    short8v aq1 = frag4(*(const uint4*)(qbase + 32));

    const u16* kbase = kb + (size_t)bh * TT * HD + lo * HD + quad * 8;
    const u16* vbase = vtb + (size_t)bh * HD * TT + lo * TT + quad * 8;
    const float* bbase = bias + (size_t)qrow * TT + 4 * quad;

    uint4 kq[4][2], vq[4][2];
    float4 bc[4];
    #pragma unroll
    for (int nt = 0; nt < 4; ++nt) {
        kq[nt][0] = *(const uint4*)(kbase + nt * 16 * HD);
        kq[nt][1] = *(const uint4*)(kbase + nt * 16 * HD + 32);
        vq[nt][0] = *(const uint4*)(vbase + nt * 16 * TT);
        vq[nt][1] = *(const uint4*)(vbase + nt * 16 * TT + 32);
        bc[nt]    = *(const float4*)(bbase + nt * 16);
    }

    float4v oacc[4] = {};                 // [dt]: O(q=4*quad+r, d=16dt+lo)
    float lacc[4] = {0.f, 0.f, 0.f, 0.f}; // partial row-sums for q-row = lo

    for (int kt = 0; kt < TT / 64; ++kt) {
        __builtin_amdgcn_s_barrier();     // raw: lockstep only, no vmcnt drain
        const int kn = (kt < 31 ? kt + 1 : 31);

        // S^T = K Q^T : A = K-frag (m = k-pos), B = Q-frag (n = q-row)
        float4v s[4] = {};
        #pragma unroll
        for (int nt = 0; nt < 4; ++nt) {
            s[nt] = MFMA16(frag4(kq[nt][0]), aq0, s[nt]);
            s[nt] = MFMA16(frag4(kq[nt][1]), aq1, s[nt]);
        }
        // reload K frags for next tile (consumed above; WAR-safe)
        #pragma unroll
        for (int nt = 0; nt < 4; ++nt) {
            kq[nt][0] = *(const uint4*)(kbase + kn * 64 * HD + nt * 16 * HD);
            kq[nt][1] = *(const uint4*)(kbase + kn * 64 * HD + nt * 16 * HD + 32);
        }

        // p = exp2(s + bias*log2e); lane holds P(q=lo, k=nt*16+4*quad+r)
        unsigned w[8];
        #pragma unroll
        for (int nt = 0; nt < 4; ++nt) {
            float p0 = __builtin_amdgcn_exp2f(fmaf(bc[nt].x, LOG2E, s[nt][0]));
            float p1 = __builtin_amdgcn_exp2f(fmaf(bc[nt].y, LOG2E, s[nt][1]));
            float p2 = __builtin_amdgcn_exp2f(fmaf(bc[nt].z, LOG2E, s[nt][2]));
            float p3 = __builtin_amdgcn_exp2f(fmaf(bc[nt].w, LOG2E, s[nt][3]));
            lacc[nt] += (p0 + p1) + (p2 + p3);
            w[2 * nt]     = pk2(p0, p1);   // W[nt][0]: k = nt*16+4q+{0,1}
            w[2 * nt + 1] = pk2(p2, p3);   // W[nt][1]: k = nt*16+4q+{2,3}
        }
        // reload bias for next tile
        #pragma unroll
        for (int nt = 0; nt < 4; ++nt)
            bc[nt] = *(const float4*)(bbase + kn * 64 + nt * 16);

        // quad redistribution: C-layout (4 k per quad) -> A-layout (8 k per quad)
        // per kf: chain(W[nt][i], W[nt+1][i]) = p32swap then p16swap
        pl32swap(w[0], w[2]); pl16swap(w[0], w[2]);   // -> a[kf0][0], a[kf0][2]
        pl32swap(w[1], w[3]); pl16swap(w[1], w[3]);   // -> a[kf0][1], a[kf0][3]
        pl32swap(w[4], w[6]); pl16swap(w[4], w[6]);   // -> a[kf1][0], a[kf1][2]
        pl32swap(w[5], w[7]); pl16swap(w[5], w[7]);   // -> a[kf1][1], a[kf1][3]
        short8v pa0 = frag4(make_uint4(w[0], w[1], w[2], w[3]));
        short8v pa1 = frag4(make_uint4(w[4], w[5], w[6], w[7]));

        // O += P V  (A = P-frag, B = V^T frag, both in registers)
        #pragma unroll
        for (int dt = 0; dt < 4; ++dt) {
            oacc[dt] = MFMA16(pa0, frag4(vq[dt][0]), oacc[dt]);
            oacc[dt] = MFMA16(pa1, frag4(vq[dt][1]), oacc[dt]);
        }
        // reload V frags for next tile
        #pragma unroll
        for (int dt = 0; dt < 4; ++dt) {
            vq[dt][0] = *(const uint4*)(vbase + dt * 16 * TT + kn * 64);
            vq[dt][1] = *(const uint4*)(vbase + dt * 16 * TT + kn * 64 + 32);
        }
    }

    float l = (lacc[0] + lacc[1]) + (lacc[2] + lacc[3]);
    l += __shfl_xor(l, 16);
    l += __shfl_xor(l, 32);                 // all lanes hold l(row=lo)
    #pragma unroll
    for (int r = 0; r < 4; ++r) {
        float lr = __shfl(l, 4 * quad + r); // l for output row 4*quad+r
        float inv = 1.f / lr;
        u16* gp = ob + ((size_t)b * TT + q0 + 16 * wv + 4 * quad + r) * DDIM + h * HD + lo;
        #pragma unroll
        for (int dt = 0; dt < 4; ++dt)
            gp[dt * 16] = f2bu(oacc[dt][r] * inv);
    }
}

// ---------------------------------------------------------------------------
// K3: out = O @ w_proj (MFMA), f32 output. Direct-fragment, no LDS.
// ---------------------------------------------------------------------------
__global__ __launch_bounds__(256) void proj_kernel(
    const u16* __restrict__ o, const u16* __restrict__ wt, float* __restrict__ out)
{
    const int t = threadIdx.x;
    const int wv = t >> 6, lane = t & 63, quad = lane >> 4, lo = lane & 15;
    const int r0 = blockIdx.y * 64, c0 = blockIdx.x * 64;

    const u16* abase = o + (size_t)(r0 + 16 * wv + lo) * DDIM + quad * 8;
    const u16* bbase = wt + (size_t)(c0 + lo) * DDIM + quad * 8;

    uint4 af[2], bf[4][2];
    af[0] = *(const uint4*)(abase);
    af[1] = *(const uint4*)(abase + 32);
    #pragma unroll
    for (int nt = 0; nt < 4; ++nt) {
        bf[nt][0] = *(const uint4*)(bbase + nt * 16 * DDIM);
        bf[nt][1] = *(const uint4*)(bbase + nt * 16 * DDIM + 32);
    }

    float4v acc[4] = {};
    for (int kk = 0; kk < 6; ++kk) {
        __builtin_amdgcn_s_barrier();
        const int kn = (kk < 5 ? kk + 1 : 5) * 64;
        short8v a0 = frag4(af[0]), a1 = frag4(af[1]);
        #pragma unroll
        for (int nt = 0; nt < 4; ++nt) {
            acc[nt] = MFMA16(a0, frag4(bf[nt][0]), acc[nt]);
            acc[nt] = MFMA16(a1, frag4(bf[nt][1]), acc[nt]);
        }
        af[0] = *(const uint4*)(abase + kn);
        af[1] = *(const uint4*)(abase + kn + 32);
        #pragma unroll
        for (int nt = 0; nt < 4; ++nt) {
            bf[nt][0] = *(const uint4*)(bbase + nt * 16 * DDIM + kn);
            bf[nt][1] = *(const uint4*)(bbase + nt * 16 * DDIM + kn + 32);
        }
    }
    #pragma unroll
    for (int r = 0; r < 4; ++r) {
        float* gp = out + (size_t)(r0 + 16 * wv + 4 * quad + r) * DDIM + c0;
        #pragma unroll
        for (int nt = 0; nt < 4; ++nt)
            gp[nt * 16 + lo] = acc[nt][r];
    }
}

extern "C" void kernel_launch(void* const* d_in, const int* in_sizes, int n_in,
                              void* d_out, int out_size, void* d_ws, size_t ws_size,
                              hipStream_t stream) {
    const float* x     = (const float*)d_in[0];
    const float* bias  = (const float*)d_in[1];
    const float* cs    = (const float*)d_in[2];
    const float* sn    = (const float*)d_in[3];
    const float* wqkv  = (const float*)d_in[4];
    const float* wproj = (const float*)d_in[5];
    float* out = (float*)d_out;

    u16* wqkvT  = (u16*)d_ws;                         // [1152][384]
    u16* wprojT = wqkvT + (size_t)QKVC * DDIM;        // [384][384]
    u16* qb     = wprojT + (size_t)DDIM * DDIM;       // [bh][t][d]
    u16* kb     = qb + (size_t)BB * HH * TT * HD;     // [bh][t][d]
    u16* vtb    = kb + (size_t)BB * HH * TT * HD;     // [bh][d][t]
    u16* ob     = vtb + (size_t)BB * HH * TT * HD;    // [b][t][h*64+d]
    u16* xb     = ob + (size_t)BT * DDIM;             // [b*t][384] bf16 x

    prep_kernel<<<dim3(144 + BT * DDIM / 4096), 256, 0, stream>>>(
        wqkv, wproj, x, wqkvT, wprojT, xb);
    qkv_rope_kernel<<<dim3(QKVC / 64, BT / 64), 256, 0, stream>>>(
        xb, wqkvT, cs, sn, qb, kb, vtb);
    attn_kernel<<<dim3(BB * HH, TT / 64), 256, 0, stream>>>(qb, kb, vtb, bias, ob);
    proj_kernel<<<dim3(DDIM / 64, BT / 64), 256, 0, stream>>>(ob, wprojT, out);
}

// Round 3
// 179.823 us; speedup vs baseline: 2.1482x; 2.1482x over previous
//
#include <hip/hip_runtime.h>
#include <hip/hip_bf16.h>

// (B,T,D,H) = (4,2048,384,6), HD=64. Inputs/output f32; intermediates bf16.
#define BB   4
#define TT   2048
#define DDIM 384
#define HH   6
#define HD   64
#define BT   (BB*TT)
#define QKVC (3*DDIM)

#define QSCALE 0.18033688011112042f   // 0.125 * log2(e), folded into Q at RoPE
#define LOG2E  1.4426950408889634f

typedef __attribute__((ext_vector_type(4))) short short4v;
typedef __attribute__((ext_vector_type(8))) short short8v;
typedef __attribute__((ext_vector_type(4))) float float4v;
typedef unsigned short u16;

static __device__ __forceinline__ u16 f2bu(float f) {
    __hip_bfloat16 h = __float2bfloat16(f);
    return __builtin_bit_cast(u16, h);
}
static __device__ __forceinline__ unsigned pk2(float lo, float hi) {
    return (unsigned)f2bu(lo) | ((unsigned)f2bu(hi) << 16);   // v_cvt_pk_bf16_f32
}
static __device__ __forceinline__ float bu2f_lo(unsigned u) {
    return __builtin_bit_cast(float, u << 16);
}
static __device__ __forceinline__ float bu2f_hi(unsigned u) {
    return __builtin_bit_cast(float, u & 0xffff0000u);
}
static __device__ __forceinline__ short8v frag4(uint4 v) {
    return __builtin_bit_cast(short8v, v);
}
static __device__ __forceinline__ short8v ld_frag(const u16* p) {
    short4v a = *(const short4v*)p;     // 2x b64: safe for 8B-aligned rows
    short4v b = *(const short4v*)(p + 4);
    return __builtin_shufflevector(a, b, 0, 1, 2, 3, 4, 5, 6, 7);
}
static __device__ __forceinline__ void st8(u16* p, uint4 v) {
    *(uint2*)p       = make_uint2(v.x, v.y);
    *(uint2*)(p + 4) = make_uint2(v.z, v.w);
}
// permlane swaps (gfx950) — P C-layout -> A-layout redistribution (verified r2)
static __device__ __forceinline__ void pl32swap(unsigned &a, unsigned &b) {
    auto r = __builtin_amdgcn_permlane32_swap(a, b, false, false);
    a = r[0]; b = r[1];
}
static __device__ __forceinline__ void pl16swap(unsigned &a, unsigned &b) {
    auto r = __builtin_amdgcn_permlane16_swap(a, b, false, false);
    a = r[0]; b = r[1];
}

#define MFMA16(a, b, c) __builtin_amdgcn_mfma_f32_16x16x32_bf16((a), (b), (c), 0, 0, 0)

// ---------------------------------------------------------------------------
// K0 (merged prep): [0,108): wqkv^T ; [108,144): wproj^T ; [144,912): x->bf16;
// [912,1936): bias*log2e -> bf16 (only launched if workspace fits).
// ---------------------------------------------------------------------------
__global__ __launch_bounds__(256) void prep_kernel(
    const float* __restrict__ wqkv, const float* __restrict__ wproj,
    const float* __restrict__ x, const float* __restrict__ bias,
    u16* __restrict__ wqkvT, u16* __restrict__ wprojT,
    u16* __restrict__ xb, u16* __restrict__ bias16)
{
    const int bid = blockIdx.x;
    const int t = threadIdx.x;
    if (bid >= 144) {
        const float* src; u16* dst; float scl; size_t base;
        if (bid < 912) { src = x;    dst = xb;     scl = 1.0f;
                         base = (size_t)(bid - 144) * 4096 + (size_t)t * 16; }
        else           { src = bias; dst = bias16; scl = LOG2E;
                         base = (size_t)(bid - 912) * 4096 + (size_t)t * 16; }
        const float* gp = src + base;
        __align__(16) u16 tmp[16];
        #pragma unroll
        for (int u = 0; u < 4; ++u) {
            float4 v = *(const float4*)(gp + 4 * u);
            tmp[4 * u + 0] = f2bu(v.x * scl); tmp[4 * u + 1] = f2bu(v.y * scl);
            tmp[4 * u + 2] = f2bu(v.z * scl); tmp[4 * u + 3] = f2bu(v.w * scl);
        }
        *(uint4*)(dst + base)     = *(const uint4*)tmp;
        *(uint4*)(dst + base + 8) = *(const uint4*)(tmp + 8);
        return;
    }
    const float* in; u16* out; int K, C, c0, k0;
    if (bid < 108) { in = wqkv;  out = wqkvT;  K = DDIM; C = QKVC;
                     c0 = (bid % 18) * 64; k0 = (bid / 18) * 64; }
    else           { int b2 = bid - 108; in = wproj; out = wprojT; K = DDIM; C = DDIM;
                     c0 = (b2 % 6) * 64; k0 = (b2 / 6) * 64; }
    __shared__ float tr[64][65];
    {
        int kr = t >> 2, cb = (t & 3) * 16;
        const float* gp = in + (size_t)(k0 + kr) * C + c0 + cb;
        #pragma unroll
        for (int u = 0; u < 4; ++u) {
            float4 v = *(const float4*)(gp + 4 * u);
            tr[cb + 4 * u + 0][kr] = v.x;
            tr[cb + 4 * u + 1][kr] = v.y;
            tr[cb + 4 * u + 2][kr] = v.z;
            tr[cb + 4 * u + 3][kr] = v.w;
        }
    }
    __syncthreads();
    {
        int c = t >> 2, kb = (t & 3) * 16;
        __align__(16) u16 tmp[16];
        #pragma unroll
        for (int u = 0; u < 16; ++u) tmp[u] = f2bu(tr[c][kb + u]);
        u16* op = out + (size_t)(c0 + c) * K + k0 + kb;
        *(uint4*)op       = *(const uint4*)tmp;
        *(uint4*)(op + 8) = *(const uint4*)(tmp + 8);
    }
}

// ---------------------------------------------------------------------------
// K1: qkv = xb @ wqkvT, RoPE fused (round-0 LDS ping-pong structure).
// Q pre-scaled by 0.125*log2e -> attn exp is exp2(s + b16).
//   q,k -> [bh][t][d] bf16 ; v -> TRANSPOSED [bh][d][t] bf16.
// ---------------------------------------------------------------------------
__global__ __launch_bounds__(256) void qkv_rope_kernel(
    const u16* __restrict__ xb, const u16* __restrict__ wt,
    const float* __restrict__ cs, const float* __restrict__ sn,
    u16* __restrict__ qb, u16* __restrict__ kb, u16* __restrict__ vtb)
{
    __shared__ __align__(16) u16 xs[2][64][68];
    __shared__ __align__(16) u16 ws[2][64][68];
    const int t = threadIdx.x;
    const int wv = t >> 6, lane = t & 63, quad = lane >> 4, lo = lane & 15;
    const int r0 = blockIdx.y * 64;
    const int c0 = blockIdx.x * 64;
    const int sr = t >> 3, sd = (t & 7) * 8;

    st8(&xs[0][sr][sd],      *(const uint4*)(xb + (size_t)(r0 + sr) * DDIM + sd));
    st8(&xs[0][sr + 32][sd], *(const uint4*)(xb + (size_t)(r0 + sr + 32) * DDIM + sd));
    st8(&ws[0][sr][sd],      *(const uint4*)(wt + (size_t)(c0 + sr) * DDIM + sd));
    st8(&ws[0][sr + 32][sd], *(const uint4*)(wt + (size_t)(c0 + sr + 32) * DDIM + sd));
    __syncthreads();

    float4v acc[4] = {};
    for (int kk = 0; kk < 6; ++kk) {
        const int cur = kk & 1, nxt = cur ^ 1;
        const int kkn = (kk < 5 ? kk + 1 : 5) * 64;
        uint4 xp0 = *(const uint4*)(xb + (size_t)(r0 + sr) * DDIM + kkn + sd);
        uint4 xp1 = *(const uint4*)(xb + (size_t)(r0 + sr + 32) * DDIM + kkn + sd);
        uint4 wp0 = *(const uint4*)(wt + (size_t)(c0 + sr) * DDIM + kkn + sd);
        uint4 wp1 = *(const uint4*)(wt + (size_t)(c0 + sr + 32) * DDIM + kkn + sd);

        #pragma unroll
        for (int kf = 0; kf < 2; ++kf) {
            short8v a = ld_frag(&xs[cur][16 * wv + lo][kf * 32 + quad * 8]);
            #pragma unroll
            for (int nt = 0; nt < 4; ++nt) {
                short8v b = ld_frag(&ws[cur][nt * 16 + lo][kf * 32 + quad * 8]);
                acc[nt] = MFMA16(a, b, acc[nt]);
            }
        }
        st8(&xs[nxt][sr][sd], xp0);
        st8(&xs[nxt][sr + 32][sd], xp1);
        st8(&ws[nxt][sr][sd], wp0);
        st8(&ws[nxt][sr + 32][sd], wp1);
        __syncthreads();
    }

    const int sec = blockIdx.x / 6;     // 0=q, 1=k, 2=v
    const int h   = blockIdx.x % 6;
    const int rbase = r0 + 16 * wv + 4 * quad;
    const int bidx  = r0 >> 11;
    const int tbase = rbase & (TT - 1);

    if (sec == 2) {
        #pragma unroll
        for (int nt = 0; nt < 4; ++nt) {
            int d = nt * 16 + lo;
            unsigned a0 = pk2(acc[nt][0], acc[nt][1]);
            unsigned a1 = pk2(acc[nt][2], acc[nt][3]);
            u16* gp = vtb + ((size_t)(bidx * HH + h) * HD + d) * TT + tbase;
            *(uint2*)gp = make_uint2(a0, a1);
        }
    } else {
        u16* dst = (sec == 0) ? qb : kb;
        const float scl = (sec == 0) ? QSCALE : 1.0f;
        #pragma unroll
        for (int np = 0; np < 2; ++np) {
            #pragma unroll
            for (int r = 0; r < 4; ++r) {
                int tpos = tbase + r;
                int ci = np * 16 + lo;
                float cv = cs[tpos * 32 + ci];
                float sv = sn[tpos * 32 + ci];
                float x1 = acc[np][r], x2 = acc[np + 2][r];
                u16* gp = dst + ((size_t)(bidx * HH + h) * TT + tpos) * HD;
                gp[ci]      = f2bu((x1 * cv - x2 * sv) * scl);
                gp[ci + 32] = f2bu((x2 * cv + x1 * sv) * scl);
            }
        }
    }
}

// ---------------------------------------------------------------------------
// K2: MFMA flash attention (round-0 LDS structure) + verified upgrades:
//  - P C->A layout via cvt_pk + permlane32/16_swap (no ps LDS buffer):
//    LDS 44032 -> 34816 B -> 4 blocks/CU via __launch_bounds__(256,4).
//  - bias as bf16*log2e (B16 path): halves the 384 MB/dispatch L3 stream;
//    exp path: exp2(s + b), Q pre-scaled by 0.125*log2e.
//  - s_setprio(1) around MFMA clusters (4 independent blocks/CU).
// ---------------------------------------------------------------------------
template <bool B16>
__global__ __launch_bounds__(256, 4) void attn_kernel(
    const u16* __restrict__ qb, const u16* __restrict__ kb, const u16* __restrict__ vtb,
    const float* __restrict__ bias, const u16* __restrict__ bias16,
    u16* __restrict__ ob)
{
    __shared__ __align__(16) u16 ks[2][64][68];
    __shared__ __align__(16) u16 vt[2][64][68];

    const int t = threadIdx.x;
    const int wv = t >> 6, lane = t & 63, quad = lane >> 4, lo = lane & 15;
    const int bh = blockIdx.x;                    // bh fastest: XCD = bh % 8
    const int b = bh / HH, h = bh % HH;
    const int q0 = blockIdx.y * 64;
    const int qrow = q0 + 16 * wv + lo;           // q-row owned by this lane

    // Q fragments (B-operand of S^T): straight from global, row-contiguous
    const u16* qbase = qb + ((size_t)bh * TT + qrow) * HD + quad * 8;
    short8v aq0 = frag4(*(const uint4*)qbase);
    short8v aq1 = frag4(*(const uint4*)(qbase + 32));

    const int sr = t >> 3, sd = (t & 7) * 8;
    const u16* kbbase = kb + (size_t)bh * TT * HD;
    const u16* vtbase = vtb + (size_t)bh * HD * TT;
    const float* brow = bias + (size_t)qrow * TT + 4 * quad;
    const u16* brow16 = bias16 + (size_t)qrow * TT + 4 * quad;

    st8(&ks[0][sr][sd],      *(const uint4*)(kbbase + (size_t)sr * HD + sd));
    st8(&ks[0][sr + 32][sd], *(const uint4*)(kbbase + (size_t)(sr + 32) * HD + sd));
    st8(&vt[0][sr][sd],      *(const uint4*)(vtbase + (size_t)sr * TT + sd));
    st8(&vt[0][sr + 32][sd], *(const uint4*)(vtbase + (size_t)(sr + 32) * TT + sd));
    float4 bcur[4]; uint2 bcur16[4];
    #pragma unroll
    for (int nt = 0; nt < 4; ++nt) {
        if constexpr (B16) bcur16[nt] = *(const uint2*)(brow16 + nt * 16);
        else               bcur[nt]   = *(const float4*)(brow + nt * 16);
    }
    __syncthreads();

    float4v oacc[4] = {};                 // [dt]: O(q=16wv+4*quad+r, d=16dt+lo)
    float lacc[4] = {0.f, 0.f, 0.f, 0.f}; // partial row-sums for q-row = lo

    for (int kt = 0; kt < TT / 64; ++kt) {
        const int cur = kt & 1, nxt = cur ^ 1;
        const int kn = (kt < 31 ? kt + 1 : 31) * 64;

        uint4 kp0 = *(const uint4*)(kbbase + (size_t)(kn + sr) * HD + sd);
        uint4 kp1 = *(const uint4*)(kbbase + (size_t)(kn + sr + 32) * HD + sd);
        uint4 vp0 = *(const uint4*)(vtbase + (size_t)sr * TT + kn + sd);
        uint4 vp1 = *(const uint4*)(vtbase + (size_t)(sr + 32) * TT + kn + sd);
        float4 bnxt[4]; uint2 bnxt16[4];
        #pragma unroll
        for (int nt = 0; nt < 4; ++nt) {
            if constexpr (B16) bnxt16[nt] = *(const uint2*)(brow16 + kn + nt * 16);
            else               bnxt[nt]   = *(const float4*)(brow + kn + nt * 16);
        }

        // S^T = K Q^T : A = K-frag (m = k-pos), B = Q-frag (n = q-row)
        float4v s[4] = {};
        __builtin_amdgcn_s_setprio(1);
        #pragma unroll
        for (int kf = 0; kf < 2; ++kf) {
            #pragma unroll
            for (int nt = 0; nt < 4; ++nt) {
                short8v kfr = ld_frag(&ks[cur][nt * 16 + lo][kf * 32 + quad * 8]);
                s[nt] = MFMA16(kfr, (kf ? aq1 : aq0), s[nt]);
            }
        }
        __builtin_amdgcn_s_setprio(0);

        // p = exp2(s + b); lane holds P(q=lo, k=nt*16+4*quad+r)
        unsigned w[8];
        #pragma unroll
        for (int nt = 0; nt < 4; ++nt) {
            float b0, b1, b2, b3;
            if constexpr (B16) {
                b0 = bu2f_lo(bcur16[nt].x); b1 = bu2f_hi(bcur16[nt].x);
                b2 = bu2f_lo(bcur16[nt].y); b3 = bu2f_hi(bcur16[nt].y);
            } else {
                b0 = bcur[nt].x * LOG2E; b1 = bcur[nt].y * LOG2E;
                b2 = bcur[nt].z * LOG2E; b3 = bcur[nt].w * LOG2E;
            }
            float p0 = __builtin_amdgcn_exp2f(s[nt][0] + b0);
            float p1 = __builtin_amdgcn_exp2f(s[nt][1] + b1);
            float p2 = __builtin_amdgcn_exp2f(s[nt][2] + b2);
            float p3 = __builtin_amdgcn_exp2f(s[nt][3] + b3);
            lacc[nt] += (p0 + p1) + (p2 + p3);
            w[2 * nt]     = pk2(p0, p1);   // k = nt*16+4q+{0,1}
            w[2 * nt + 1] = pk2(p2, p3);   // k = nt*16+4q+{2,3}
        }

        // C-layout (4 k per quad) -> A-layout (8 k per quad), in-register
        pl32swap(w[0], w[2]); pl16swap(w[0], w[2]);
        pl32swap(w[1], w[3]); pl16swap(w[1], w[3]);
        pl32swap(w[4], w[6]); pl16swap(w[4], w[6]);
        pl32swap(w[5], w[7]); pl16swap(w[5], w[7]);
        short8v pa0 = frag4(make_uint4(w[0], w[1], w[2], w[3]));
        short8v pa1 = frag4(make_uint4(w[4], w[5], w[6], w[7]));

        // O += P V  via 16x16x32: A = P-frag (regs), B = V^T from LDS
        __builtin_amdgcn_s_setprio(1);
        #pragma unroll
        for (int kf = 0; kf < 2; ++kf) {
            #pragma unroll
            for (int dt = 0; dt < 4; ++dt) {
                short8v bv = ld_frag(&vt[cur][dt * 16 + lo][kf * 32 + quad * 8]);
                oacc[dt] = MFMA16((kf ? pa1 : pa0), bv, oacc[dt]);
            }
        }
        __builtin_amdgcn_s_setprio(0);

        st8(&ks[nxt][sr][sd], kp0);
        st8(&ks[nxt][sr + 32][sd], kp1);
        st8(&vt[nxt][sr][sd], vp0);
        st8(&vt[nxt][sr + 32][sd], vp1);
        #pragma unroll
        for (int nt = 0; nt < 4; ++nt) {
            if constexpr (B16) bcur16[nt] = bnxt16[nt];
            else               bcur[nt]   = bnxt[nt];
        }
        __syncthreads();
    }

    float l = (lacc[0] + lacc[1]) + (lacc[2] + lacc[3]);
    l += __shfl_xor(l, 16);
    l += __shfl_xor(l, 32);                 // all lanes hold l(row=lo)
    #pragma unroll
    for (int r = 0; r < 4; ++r) {
        float lr = __shfl(l, 4 * quad + r); // l for output row 4*quad+r
        float inv = 1.f / lr;
        u16* gp = ob + ((size_t)b * TT + q0 + 16 * wv + 4 * quad + r) * DDIM + h * HD + lo;
        #pragma unroll
        for (int dt = 0; dt < 4; ++dt)
            gp[dt * 16] = f2bu(oacc[dt][r] * inv);
    }
}

// ---------------------------------------------------------------------------
// K3: out = O @ w_proj (MFMA), f32 output. Ping-pong + prefetch (round-0).
// ---------------------------------------------------------------------------
__global__ __launch_bounds__(256) void proj_kernel(
    const u16* __restrict__ o, const u16* __restrict__ wt, float* __restrict__ out)
{
    __shared__ __align__(16) u16 os[2][64][68];
    __shared__ __align__(16) u16 ws[2][64][68];
    const int t = threadIdx.x;
    const int wv = t >> 6, lane = t & 63, quad = lane >> 4, lo = lane & 15;
    const int r0 = blockIdx.y * 64, c0 = blockIdx.x * 64;
    const int sr = t >> 3, sd = (t & 7) * 8;

    st8(&os[0][sr][sd],      *(const uint4*)(o + (size_t)(r0 + sr) * DDIM + sd));
    st8(&os[0][sr + 32][sd], *(const uint4*)(o + (size_t)(r0 + sr + 32) * DDIM + sd));
    st8(&ws[0][sr][sd],      *(const uint4*)(wt + (size_t)(c0 + sr) * DDIM + sd));
    st8(&ws[0][sr + 32][sd], *(const uint4*)(wt + (size_t)(c0 + sr + 32) * DDIM + sd));
    __syncthreads();

    float4v acc[4] = {};
    for (int kk = 0; kk < 6; ++kk) {
        const int cur = kk & 1, nxt = cur ^ 1;
        const int kkn = (kk < 5 ? kk + 1 : 5) * 64;
        uint4 op0 = *(const uint4*)(o + (size_t)(r0 + sr) * DDIM + kkn + sd);
        uint4 op1 = *(const uint4*)(o + (size_t)(r0 + sr + 32) * DDIM + kkn + sd);
        uint4 wp0 = *(const uint4*)(wt + (size_t)(c0 + sr) * DDIM + kkn + sd);
        uint4 wp1 = *(const uint4*)(wt + (size_t)(c0 + sr + 32) * DDIM + kkn + sd);

        #pragma unroll
        for (int kf = 0; kf < 2; ++kf) {
            short8v a = ld_frag(&os[cur][16 * wv + lo][kf * 32 + quad * 8]);
            #pragma unroll
            for (int nt = 0; nt < 4; ++nt) {
                short8v bfr = ld_frag(&ws[cur][nt * 16 + lo][kf * 32 + quad * 8]);
                acc[nt] = MFMA16(a, bfr, acc[nt]);
            }
        }
        st8(&os[nxt][sr][sd], op0);
        st8(&os[nxt][sr + 32][sd], op1);
        st8(&ws[nxt][sr][sd], wp0);
        st8(&ws[nxt][sr + 32][sd], wp1);
        __syncthreads();
    }
    #pragma unroll
    for (int r = 0; r < 4; ++r) {
        float* gp = out + (size_t)(r0 + 16 * wv + 4 * quad + r) * DDIM + c0;
        #pragma unroll
        for (int nt = 0; nt < 4; ++nt)
            gp[nt * 16 + lo] = acc[nt][r];
    }
}

extern "C" void kernel_launch(void* const* d_in, const int* in_sizes, int n_in,
                              void* d_out, int out_size, void* d_ws, size_t ws_size,
                              hipStream_t stream) {
    const float* x     = (const float*)d_in[0];
    const float* bias  = (const float*)d_in[1];
    const float* cs    = (const float*)d_in[2];
    const float* sn    = (const float*)d_in[3];
    const float* wqkv  = (const float*)d_in[4];
    const float* wproj = (const float*)d_in[5];
    float* out = (float*)d_out;

    u16* wqkvT  = (u16*)d_ws;                         // [1152][384]
    u16* wprojT = wqkvT + (size_t)QKVC * DDIM;        // [384][384]
    u16* qb     = wprojT + (size_t)DDIM * DDIM;       // [bh][t][d]
    u16* kb     = qb + (size_t)BB * HH * TT * HD;     // [bh][t][d]
    u16* vtb    = kb + (size_t)BB * HH * TT * HD;     // [bh][d][t]
    u16* ob     = vtb + (size_t)BB * HH * TT * HD;    // [b][t][h*64+d]
    u16* xb     = ob + (size_t)BT * DDIM;             // [b*t][384] bf16 x
    u16* bias16 = xb + (size_t)BT * DDIM;             // [T][T] bf16 bias*log2e

    const size_t need_b16 = ((size_t)(bias16 - wqkvT) + (size_t)TT * TT) * sizeof(u16);
    const bool useb16 = ws_size >= need_b16;

    prep_kernel<<<dim3(144 + BT * DDIM / 4096 + (useb16 ? TT * TT / 4096 : 0)),
                  256, 0, stream>>>(wqkv, wproj, x, bias, wqkvT, wprojT, xb, bias16);
    qkv_rope_kernel<<<dim3(QKVC / 64, BT / 64), 256, 0, stream>>>(
        xb, wqkvT, cs, sn, qb, kb, vtb);
    if (useb16)
        attn_kernel<true><<<dim3(BB * HH, TT / 64), 256, 0, stream>>>(
            qb, kb, vtb, bias, bias16, ob);
    else
        attn_kernel<false><<<dim3(BB * HH, TT / 64), 256, 0, stream>>>(
            qb, kb, vtb, bias, bias16, ob);
    proj_kernel<<<dim3(DDIM / 64, BT / 64), 256, 0, stream>>>(ob, wprojT, out);
}

// Round 4
// 178.690 us; speedup vs baseline: 2.1618x; 1.0063x over previous
//
#include <hip/hip_runtime.h>
#include <hip/hip_bf16.h>

// (B,T,D,H) = (4,2048,384,6), HD=64. Inputs/output f32; intermediates bf16.
#define BB   4
#define TT   2048
#define DDIM 384
#define HH   6
#define HD   64
#define BT   (BB*TT)
#define QKVC (3*DDIM)

#define QSCALE 0.18033688011112042f   // 0.125 * log2(e), folded into Q at RoPE
#define LOG2E  1.4426950408889634f

typedef __attribute__((ext_vector_type(4))) short short4v;
typedef __attribute__((ext_vector_type(8))) short short8v;
typedef __attribute__((ext_vector_type(4))) float float4v;
typedef unsigned short u16;

static __device__ __forceinline__ u16 f2bu(float f) {
    __hip_bfloat16 h = __float2bfloat16(f);
    return __builtin_bit_cast(u16, h);
}
static __device__ __forceinline__ unsigned pk2(float lo, float hi) {
    return (unsigned)f2bu(lo) | ((unsigned)f2bu(hi) << 16);   // v_cvt_pk_bf16_f32
}
static __device__ __forceinline__ float bu2f_lo(unsigned u) {
    return __builtin_bit_cast(float, u << 16);
}
static __device__ __forceinline__ float bu2f_hi(unsigned u) {
    return __builtin_bit_cast(float, u & 0xffff0000u);
}
static __device__ __forceinline__ short8v frag4(uint4 v) {
    return __builtin_bit_cast(short8v, v);
}
static __device__ __forceinline__ short8v ld_frag(const u16* p) {
    short4v a = *(const short4v*)p;     // 2x b64: safe for 8B-aligned rows
    short4v b = *(const short4v*)(p + 4);
    return __builtin_shufflevector(a, b, 0, 1, 2, 3, 4, 5, 6, 7);
}
static __device__ __forceinline__ void st8(u16* p, uint4 v) {
    *(uint2*)p       = make_uint2(v.x, v.y);
    *(uint2*)(p + 4) = make_uint2(v.z, v.w);
}
// permlane swaps (gfx950) — P C-layout -> A-layout redistribution (verified r2)
static __device__ __forceinline__ void pl32swap(unsigned &a, unsigned &b) {
    auto r = __builtin_amdgcn_permlane32_swap(a, b, false, false);
    a = r[0]; b = r[1];
}
static __device__ __forceinline__ void pl16swap(unsigned &a, unsigned &b) {
    auto r = __builtin_amdgcn_permlane16_swap(a, b, false, false);
    a = r[0]; b = r[1];
}

#define MFMA16(a, b, c) __builtin_amdgcn_mfma_f32_16x16x32_bf16((a), (b), (c), 0, 0, 0)
// Pin: forbid the scheduler from sinking the prefetch loads below this point
// (r3 post-mortem: VGPR=52 proved loads were sunk to their use at loop bottom,
// defeating the software prefetch and exposing full L2 latency per iteration).
#define PIN_PREFETCH() __builtin_amdgcn_sched_barrier(0)

// ---------------------------------------------------------------------------
// K0 (merged prep): [0,108): wqkv^T ; [108,144): wproj^T ; [144,912): x->bf16;
// [912,1936): bias*log2e -> bf16 (only launched if workspace fits).
// ---------------------------------------------------------------------------
__global__ __launch_bounds__(256) void prep_kernel(
    const float* __restrict__ wqkv, const float* __restrict__ wproj,
    const float* __restrict__ x, const float* __restrict__ bias,
    u16* __restrict__ wqkvT, u16* __restrict__ wprojT,
    u16* __restrict__ xb, u16* __restrict__ bias16)
{
    const int bid = blockIdx.x;
    const int t = threadIdx.x;
    if (bid >= 144) {
        const float* src; u16* dst; float scl; size_t base;
        if (bid < 912) { src = x;    dst = xb;     scl = 1.0f;
                         base = (size_t)(bid - 144) * 4096 + (size_t)t * 16; }
        else           { src = bias; dst = bias16; scl = LOG2E;
                         base = (size_t)(bid - 912) * 4096 + (size_t)t * 16; }
        const float* gp = src + base;
        __align__(16) u16 tmp[16];
        #pragma unroll
        for (int u = 0; u < 4; ++u) {
            float4 v = *(const float4*)(gp + 4 * u);
            tmp[4 * u + 0] = f2bu(v.x * scl); tmp[4 * u + 1] = f2bu(v.y * scl);
            tmp[4 * u + 2] = f2bu(v.z * scl); tmp[4 * u + 3] = f2bu(v.w * scl);
        }
        *(uint4*)(dst + base)     = *(const uint4*)tmp;
        *(uint4*)(dst + base + 8) = *(const uint4*)(tmp + 8);
        return;
    }
    const float* in; u16* out; int K, C, c0, k0;
    if (bid < 108) { in = wqkv;  out = wqkvT;  K = DDIM; C = QKVC;
                     c0 = (bid % 18) * 64; k0 = (bid / 18) * 64; }
    else           { int b2 = bid - 108; in = wproj; out = wprojT; K = DDIM; C = DDIM;
                     c0 = (b2 % 6) * 64; k0 = (b2 / 6) * 64; }
    __shared__ float tr[64][65];
    {
        int kr = t >> 2, cb = (t & 3) * 16;
        const float* gp = in + (size_t)(k0 + kr) * C + c0 + cb;
        #pragma unroll
        for (int u = 0; u < 4; ++u) {
            float4 v = *(const float4*)(gp + 4 * u);
            tr[cb + 4 * u + 0][kr] = v.x;
            tr[cb + 4 * u + 1][kr] = v.y;
            tr[cb + 4 * u + 2][kr] = v.z;
            tr[cb + 4 * u + 3][kr] = v.w;
        }
    }
    __syncthreads();
    {
        int c = t >> 2, kb = (t & 3) * 16;
        __align__(16) u16 tmp[16];
        #pragma unroll
        for (int u = 0; u < 16; ++u) tmp[u] = f2bu(tr[c][kb + u]);
        u16* op = out + (size_t)(c0 + c) * K + k0 + kb;
        *(uint4*)op       = *(const uint4*)tmp;
        *(uint4*)(op + 8) = *(const uint4*)(tmp + 8);
    }
}

// ---------------------------------------------------------------------------
// K1: qkv = xb @ wqkvT, RoPE fused (LDS ping-pong + pinned prefetch).
// Q pre-scaled by 0.125*log2e -> attn exp is exp2(s + b16).
//   q,k -> [bh][t][d] bf16 ; v -> TRANSPOSED [bh][d][t] bf16.
// ---------------------------------------------------------------------------
__global__ __launch_bounds__(256, 4) void qkv_rope_kernel(
    const u16* __restrict__ xb, const u16* __restrict__ wt,
    const float* __restrict__ cs, const float* __restrict__ sn,
    u16* __restrict__ qb, u16* __restrict__ kb, u16* __restrict__ vtb)
{
    __shared__ __align__(16) u16 xs[2][64][68];
    __shared__ __align__(16) u16 ws[2][64][68];
    const int t = threadIdx.x;
    const int wv = t >> 6, lane = t & 63, quad = lane >> 4, lo = lane & 15;
    const int r0 = blockIdx.y * 64;
    const int c0 = blockIdx.x * 64;
    const int sr = t >> 3, sd = (t & 7) * 8;

    st8(&xs[0][sr][sd],      *(const uint4*)(xb + (size_t)(r0 + sr) * DDIM + sd));
    st8(&xs[0][sr + 32][sd], *(const uint4*)(xb + (size_t)(r0 + sr + 32) * DDIM + sd));
    st8(&ws[0][sr][sd],      *(const uint4*)(wt + (size_t)(c0 + sr) * DDIM + sd));
    st8(&ws[0][sr + 32][sd], *(const uint4*)(wt + (size_t)(c0 + sr + 32) * DDIM + sd));
    __syncthreads();

    float4v acc[4] = {};
    for (int kk = 0; kk < 6; ++kk) {
        const int cur = kk & 1, nxt = cur ^ 1;
        const int kkn = (kk < 5 ? kk + 1 : 5) * 64;
        uint4 xp0 = *(const uint4*)(xb + (size_t)(r0 + sr) * DDIM + kkn + sd);
        uint4 xp1 = *(const uint4*)(xb + (size_t)(r0 + sr + 32) * DDIM + kkn + sd);
        uint4 wp0 = *(const uint4*)(wt + (size_t)(c0 + sr) * DDIM + kkn + sd);
        uint4 wp1 = *(const uint4*)(wt + (size_t)(c0 + sr + 32) * DDIM + kkn + sd);
        PIN_PREFETCH();

        #pragma unroll
        for (int kf = 0; kf < 2; ++kf) {
            short8v a = ld_frag(&xs[cur][16 * wv + lo][kf * 32 + quad * 8]);
            #pragma unroll
            for (int nt = 0; nt < 4; ++nt) {
                short8v b = ld_frag(&ws[cur][nt * 16 + lo][kf * 32 + quad * 8]);
                acc[nt] = MFMA16(a, b, acc[nt]);
            }
        }
        st8(&xs[nxt][sr][sd], xp0);
        st8(&xs[nxt][sr + 32][sd], xp1);
        st8(&ws[nxt][sr][sd], wp0);
        st8(&ws[nxt][sr + 32][sd], wp1);
        __syncthreads();
    }

    const int sec = blockIdx.x / 6;     // 0=q, 1=k, 2=v
    const int h   = blockIdx.x % 6;
    const int rbase = r0 + 16 * wv + 4 * quad;
    const int bidx  = r0 >> 11;
    const int tbase = rbase & (TT - 1);

    if (sec == 2) {
        #pragma unroll
        for (int nt = 0; nt < 4; ++nt) {
            int d = nt * 16 + lo;
            unsigned a0 = pk2(acc[nt][0], acc[nt][1]);
            unsigned a1 = pk2(acc[nt][2], acc[nt][3]);
            u16* gp = vtb + ((size_t)(bidx * HH + h) * HD + d) * TT + tbase;
            *(uint2*)gp = make_uint2(a0, a1);
        }
    } else {
        u16* dst = (sec == 0) ? qb : kb;
        const float scl = (sec == 0) ? QSCALE : 1.0f;
        #pragma unroll
        for (int np = 0; np < 2; ++np) {
            #pragma unroll
            for (int r = 0; r < 4; ++r) {
                int tpos = tbase + r;
                int ci = np * 16 + lo;
                float cv = cs[tpos * 32 + ci];
                float sv = sn[tpos * 32 + ci];
                float x1 = acc[np][r], x2 = acc[np + 2][r];
                u16* gp = dst + ((size_t)(bidx * HH + h) * TT + tpos) * HD;
                gp[ci]      = f2bu((x1 * cv - x2 * sv) * scl);
                gp[ci + 32] = f2bu((x2 * cv + x1 * sv) * scl);
            }
        }
    }
}

// ---------------------------------------------------------------------------
// K2: MFMA flash attention:
//  - P C->A layout via cvt_pk + permlane32/16_swap (no ps LDS buffer).
//  - bias as bf16*log2e (B16 path); exp: exp2(s + b), Q pre-scaled.
//  - prefetch pinned at loop top (sched_barrier) so the iter's MFMA/VALU
//    covers the L2 latency instead of the barrier drain eating it.
//  - s_setprio(1) around MFMA clusters.
// ---------------------------------------------------------------------------
template <bool B16>
__global__ __launch_bounds__(256, 4) void attn_kernel(
    const u16* __restrict__ qb, const u16* __restrict__ kb, const u16* __restrict__ vtb,
    const float* __restrict__ bias, const u16* __restrict__ bias16,
    u16* __restrict__ ob)
{
    __shared__ __align__(16) u16 ks[2][64][68];
    __shared__ __align__(16) u16 vt[2][64][68];

    const int t = threadIdx.x;
    const int wv = t >> 6, lane = t & 63, quad = lane >> 4, lo = lane & 15;
    const int bh = blockIdx.x;                    // bh fastest: XCD = bh % 8
    const int b = bh / HH, h = bh % HH;
    const int q0 = blockIdx.y * 64;
    const int qrow = q0 + 16 * wv + lo;           // q-row owned by this lane

    // Q fragments (B-operand of S^T): straight from global, row-contiguous
    const u16* qbase = qb + ((size_t)bh * TT + qrow) * HD + quad * 8;
    short8v aq0 = frag4(*(const uint4*)qbase);
    short8v aq1 = frag4(*(const uint4*)(qbase + 32));

    const int sr = t >> 3, sd = (t & 7) * 8;
    const u16* kbbase = kb + (size_t)bh * TT * HD;
    const u16* vtbase = vtb + (size_t)bh * HD * TT;
    const float* brow = bias + (size_t)qrow * TT + 4 * quad;
    const u16* brow16 = bias16 + (size_t)qrow * TT + 4 * quad;

    st8(&ks[0][sr][sd],      *(const uint4*)(kbbase + (size_t)sr * HD + sd));
    st8(&ks[0][sr + 32][sd], *(const uint4*)(kbbase + (size_t)(sr + 32) * HD + sd));
    st8(&vt[0][sr][sd],      *(const uint4*)(vtbase + (size_t)sr * TT + sd));
    st8(&vt[0][sr + 32][sd], *(const uint4*)(vtbase + (size_t)(sr + 32) * TT + sd));
    float4 bcur[4]; uint2 bcur16[4];
    #pragma unroll
    for (int nt = 0; nt < 4; ++nt) {
        if constexpr (B16) bcur16[nt] = *(const uint2*)(brow16 + nt * 16);
        else               bcur[nt]   = *(const float4*)(brow + nt * 16);
    }
    __syncthreads();

    float4v oacc[4] = {};                 // [dt]: O(q=16wv+4*quad+r, d=16dt+lo)
    float lacc[4] = {0.f, 0.f, 0.f, 0.f}; // partial row-sums for q-row = lo

    for (int kt = 0; kt < TT / 64; ++kt) {
        const int cur = kt & 1, nxt = cur ^ 1;
        const int kn = (kt < 31 ? kt + 1 : 31) * 64;

        uint4 kp0 = *(const uint4*)(kbbase + (size_t)(kn + sr) * HD + sd);
        uint4 kp1 = *(const uint4*)(kbbase + (size_t)(kn + sr + 32) * HD + sd);
        uint4 vp0 = *(const uint4*)(vtbase + (size_t)sr * TT + kn + sd);
        uint4 vp1 = *(const uint4*)(vtbase + (size_t)(sr + 32) * TT + kn + sd);
        float4 bnxt[4]; uint2 bnxt16[4];
        #pragma unroll
        for (int nt = 0; nt < 4; ++nt) {
            if constexpr (B16) bnxt16[nt] = *(const uint2*)(brow16 + kn + nt * 16);
            else               bnxt[nt]   = *(const float4*)(brow + kn + nt * 16);
        }
        PIN_PREFETCH();   // keep all prefetch issues above the compute cluster

        // S^T = K Q^T : A = K-frag (m = k-pos), B = Q-frag (n = q-row)
        float4v s[4] = {};
        __builtin_amdgcn_s_setprio(1);
        #pragma unroll
        for (int kf = 0; kf < 2; ++kf) {
            #pragma unroll
            for (int nt = 0; nt < 4; ++nt) {
                short8v kfr = ld_frag(&ks[cur][nt * 16 + lo][kf * 32 + quad * 8]);
                s[nt] = MFMA16(kfr, (kf ? aq1 : aq0), s[nt]);
            }
        }
        __builtin_amdgcn_s_setprio(0);

        // p = exp2(s + b); lane holds P(q=lo, k=nt*16+4*quad+r)
        unsigned w[8];
        #pragma unroll
        for (int nt = 0; nt < 4; ++nt) {
            float b0, b1, b2, b3;
            if constexpr (B16) {
                b0 = bu2f_lo(bcur16[nt].x); b1 = bu2f_hi(bcur16[nt].x);
                b2 = bu2f_lo(bcur16[nt].y); b3 = bu2f_hi(bcur16[nt].y);
            } else {
                b0 = bcur[nt].x * LOG2E; b1 = bcur[nt].y * LOG2E;
                b2 = bcur[nt].z * LOG2E; b3 = bcur[nt].w * LOG2E;
            }
            float p0 = __builtin_amdgcn_exp2f(s[nt][0] + b0);
            float p1 = __builtin_amdgcn_exp2f(s[nt][1] + b1);
            float p2 = __builtin_amdgcn_exp2f(s[nt][2] + b2);
            float p3 = __builtin_amdgcn_exp2f(s[nt][3] + b3);
            lacc[nt] += (p0 + p1) + (p2 + p3);
            w[2 * nt]     = pk2(p0, p1);   // k = nt*16+4q+{0,1}
            w[2 * nt + 1] = pk2(p2, p3);   // k = nt*16+4q+{2,3}
        }

        // C-layout (4 k per quad) -> A-layout (8 k per quad), in-register
        pl32swap(w[0], w[2]); pl16swap(w[0], w[2]);
        pl32swap(w[1], w[3]); pl16swap(w[1], w[3]);
        pl32swap(w[4], w[6]); pl16swap(w[4], w[6]);
        pl32swap(w[5], w[7]); pl16swap(w[5], w[7]);
        short8v pa0 = frag4(make_uint4(w[0], w[1], w[2], w[3]));
        short8v pa1 = frag4(make_uint4(w[4], w[5], w[6], w[7]));

        // O += P V  via 16x16x32: A = P-frag (regs), B = V^T from LDS
        __builtin_amdgcn_s_setprio(1);
        #pragma unroll
        for (int kf = 0; kf < 2; ++kf) {
            #pragma unroll
            for (int dt = 0; dt < 4; ++dt) {
                short8v bv = ld_frag(&vt[cur][dt * 16 + lo][kf * 32 + quad * 8]);
                oacc[dt] = MFMA16((kf ? pa1 : pa0), bv, oacc[dt]);
            }
        }
        __builtin_amdgcn_s_setprio(0);

        st8(&ks[nxt][sr][sd], kp0);
        st8(&ks[nxt][sr + 32][sd], kp1);
        st8(&vt[nxt][sr][sd], vp0);
        st8(&vt[nxt][sr + 32][sd], vp1);
        #pragma unroll
        for (int nt = 0; nt < 4; ++nt) {
            if constexpr (B16) bcur16[nt] = bnxt16[nt];
            else               bcur[nt]   = bnxt[nt];
        }
        __syncthreads();
    }

    float l = (lacc[0] + lacc[1]) + (lacc[2] + lacc[3]);
    l += __shfl_xor(l, 16);
    l += __shfl_xor(l, 32);                 // all lanes hold l(row=lo)
    #pragma unroll
    for (int r = 0; r < 4; ++r) {
        float lr = __shfl(l, 4 * quad + r); // l for output row 4*quad+r
        float inv = 1.f / lr;
        u16* gp = ob + ((size_t)b * TT + q0 + 16 * wv + 4 * quad + r) * DDIM + h * HD + lo;
        #pragma unroll
        for (int dt = 0; dt < 4; ++dt)
            gp[dt * 16] = f2bu(oacc[dt][r] * inv);
    }
}

// ---------------------------------------------------------------------------
// K3: out = O @ w_proj (MFMA), f32 output. Ping-pong + pinned prefetch.
// ---------------------------------------------------------------------------
__global__ __launch_bounds__(256, 4) void proj_kernel(
    const u16* __restrict__ o, const u16* __restrict__ wt, float* __restrict__ out)
{
    __shared__ __align__(16) u16 os[2][64][68];
    __shared__ __align__(16) u16 ws[2][64][68];
    const int t = threadIdx.x;
    const int wv = t >> 6, lane = t & 63, quad = lane >> 4, lo = lane & 15;
    const int r0 = blockIdx.y * 64, c0 = blockIdx.x * 64;
    const int sr = t >> 3, sd = (t & 7) * 8;

    st8(&os[0][sr][sd],      *(const uint4*)(o + (size_t)(r0 + sr) * DDIM + sd));
    st8(&os[0][sr + 32][sd], *(const uint4*)(o + (size_t)(r0 + sr + 32) * DDIM + sd));
    st8(&ws[0][sr][sd],      *(const uint4*)(wt + (size_t)(c0 + sr) * DDIM + sd));
    st8(&ws[0][sr + 32][sd], *(const uint4*)(wt + (size_t)(c0 + sr + 32) * DDIM + sd));
    __syncthreads();

    float4v acc[4] = {};
    for (int kk = 0; kk < 6; ++kk) {
        const int cur = kk & 1, nxt = cur ^ 1;
        const int kkn = (kk < 5 ? kk + 1 : 5) * 64;
        uint4 op0 = *(const uint4*)(o + (size_t)(r0 + sr) * DDIM + kkn + sd);
        uint4 op1 = *(const uint4*)(o + (size_t)(r0 + sr + 32) * DDIM + kkn + sd);
        uint4 wp0 = *(const uint4*)(wt + (size_t)(c0 + sr) * DDIM + kkn + sd);
        uint4 wp1 = *(const uint4*)(wt + (size_t)(c0 + sr + 32) * DDIM + kkn + sd);
        PIN_PREFETCH();

        #pragma unroll
        for (int kf = 0; kf < 2; ++kf) {
            short8v a = ld_frag(&os[cur][16 * wv + lo][kf * 32 + quad * 8]);
            #pragma unroll
            for (int nt = 0; nt < 4; ++nt) {
                short8v bfr = ld_frag(&ws[cur][nt * 16 + lo][kf * 32 + quad * 8]);
                acc[nt] = MFMA16(a, bfr, acc[nt]);
            }
        }
        st8(&os[nxt][sr][sd], op0);
        st8(&os[nxt][sr + 32][sd], op1);
        st8(&ws[nxt][sr][sd], wp0);
        st8(&ws[nxt][sr + 32][sd], wp1);
        __syncthreads();
    }
    #pragma unroll
    for (int r = 0; r < 4; ++r) {
        float* gp = out + (size_t)(r0 + 16 * wv + 4 * quad + r) * DDIM + c0;
        #pragma unroll
        for (int nt = 0; nt < 4; ++nt)
            gp[nt * 16 + lo] = acc[nt][r];
    }
}

extern "C" void kernel_launch(void* const* d_in, const int* in_sizes, int n_in,
                              void* d_out, int out_size, void* d_ws, size_t ws_size,
                              hipStream_t stream) {
    const float* x     = (const float*)d_in[0];
    const float* bias  = (const float*)d_in[1];
    const float* cs    = (const float*)d_in[2];
    const float* sn    = (const float*)d_in[3];
    const float* wqkv  = (const float*)d_in[4];
    const float* wproj = (const float*)d_in[5];
    float* out = (float*)d_out;

    u16* wqkvT  = (u16*)d_ws;                         // [1152][384]
    u16* wprojT = wqkvT + (size_t)QKVC * DDIM;        // [384][384]
    u16* qb     = wprojT + (size_t)DDIM * DDIM;       // [bh][t][d]
    u16* kb     = qb + (size_t)BB * HH * TT * HD;     // [bh][t][d]
    u16* vtb    = kb + (size_t)BB * HH * TT * HD;     // [bh][d][t]
    u16* ob     = vtb + (size_t)BB * HH * TT * HD;    // [b][t][h*64+d]
    u16* xb     = ob + (size_t)BT * DDIM;             // [b*t][384] bf16 x
    u16* bias16 = xb + (size_t)BT * DDIM;             // [T][T] bf16 bias*log2e

    const size_t need_b16 = ((size_t)(bias16 - wqkvT) + (size_t)TT * TT) * sizeof(u16);
    const bool useb16 = ws_size >= need_b16;

    prep_kernel<<<dim3(144 + BT * DDIM / 4096 + (useb16 ? TT * TT / 4096 : 0)),
                  256, 0, stream>>>(wqkv, wproj, x, bias, wqkvT, wprojT, xb, bias16);
    qkv_rope_kernel<<<dim3(QKVC / 64, BT / 64), 256, 0, stream>>>(
        xb, wqkvT, cs, sn, qb, kb, vtb);
    if (useb16)
        attn_kernel<true><<<dim3(BB * HH, TT / 64), 256, 0, stream>>>(
            qb, kb, vtb, bias, bias16, ob);
    else
        attn_kernel<false><<<dim3(BB * HH, TT / 64), 256, 0, stream>>>(
            qb, kb, vtb, bias, bias16, ob);
    proj_kernel<<<dim3(DDIM / 64, BT / 64), 256, 0, stream>>>(ob, wprojT, out);
}

// Round 5
// 167.267 us; speedup vs baseline: 2.3094x; 1.0683x over previous
//
#include <hip/hip_runtime.h>
#include <hip/hip_bf16.h>

// (B,T,D,H) = (4,2048,384,6), HD=64. Inputs/output f32; intermediates bf16.
#define BB   4
#define TT   2048
#define DDIM 384
#define HH   6
#define HD   64
#define BT   (BB*TT)
#define QKVC (3*DDIM)

#define QSCALE 0.18033688011112042f   // 0.125 * log2(e), folded into Q at RoPE
#define LOG2E  1.4426950408889634f

typedef __attribute__((ext_vector_type(4))) short short4v;
typedef __attribute__((ext_vector_type(8))) short short8v;
typedef __attribute__((ext_vector_type(4))) float float4v;
typedef unsigned short u16;

static __device__ __forceinline__ u16 f2bu(float f) {
    __hip_bfloat16 h = __float2bfloat16(f);
    return __builtin_bit_cast(u16, h);
}
static __device__ __forceinline__ unsigned pk2(float lo, float hi) {
    return (unsigned)f2bu(lo) | ((unsigned)f2bu(hi) << 16);   // v_cvt_pk_bf16_f32
}
static __device__ __forceinline__ short8v frag4(uint4 v) {
    return __builtin_bit_cast(short8v, v);
}
static __device__ __forceinline__ short8v ld_frag(const u16* p) {
    short4v a = *(const short4v*)p;     // 2x b64: safe for 8B-aligned rows
    short4v b = *(const short4v*)(p + 4);
    return __builtin_shufflevector(a, b, 0, 1, 2, 3, 4, 5, 6, 7);
}
static __device__ __forceinline__ void st8(u16* p, uint4 v) {
    *(uint2*)p       = make_uint2(v.x, v.y);
    *(uint2*)(p + 4) = make_uint2(v.z, v.w);
}
// permlane swaps (gfx950) — P C-layout -> A-layout redistribution (verified r2)
static __device__ __forceinline__ void pl32swap(unsigned &a, unsigned &b) {
    auto r = __builtin_amdgcn_permlane32_swap(a, b, false, false);
    a = r[0]; b = r[1];
}
static __device__ __forceinline__ void pl16swap(unsigned &a, unsigned &b) {
    auto r = __builtin_amdgcn_permlane16_swap(a, b, false, false);
    a = r[0]; b = r[1];
}

#define MFMA16(a, b, c) __builtin_amdgcn_mfma_f32_16x16x32_bf16((a), (b), (c), 0, 0, 0)

// ---------------------------------------------------------------------------
// K0 (merged prep): [0,108): wqkv^T ; [108,144): wproj^T ; [144,912): x->bf16;
// [912,1936): bias zero-check -> flag (atomicOr of |bits|).
// ---------------------------------------------------------------------------
__global__ __launch_bounds__(256) void prep_kernel(
    const float* __restrict__ wqkv, const float* __restrict__ wproj,
    const float* __restrict__ x, const float* __restrict__ bias,
    u16* __restrict__ wqkvT, u16* __restrict__ wprojT,
    u16* __restrict__ xb, unsigned* __restrict__ flag)
{
    const int bid = blockIdx.x;
    const int t = threadIdx.x;
    if (bid >= 912) {   // bias nonzero check
        const float* gp = bias + (size_t)(bid - 912) * 4096 + (size_t)t * 16;
        unsigned acc = 0;
        #pragma unroll
        for (int u = 0; u < 4; ++u) {
            float4 v = *(const float4*)(gp + 4 * u);
            acc |= (__builtin_bit_cast(unsigned, v.x) & 0x7fffffffu);
            acc |= (__builtin_bit_cast(unsigned, v.y) & 0x7fffffffu);
            acc |= (__builtin_bit_cast(unsigned, v.z) & 0x7fffffffu);
            acc |= (__builtin_bit_cast(unsigned, v.w) & 0x7fffffffu);
        }
        if (acc) atomicOr(flag, 1u);
        return;
    }
    if (bid >= 144) {   // x -> bf16
        size_t base = (size_t)(bid - 144) * 4096 + (size_t)t * 16;
        const float* gp = x + base;
        __align__(16) u16 tmp[16];
        #pragma unroll
        for (int u = 0; u < 4; ++u) {
            float4 v = *(const float4*)(gp + 4 * u);
            tmp[4 * u + 0] = f2bu(v.x); tmp[4 * u + 1] = f2bu(v.y);
            tmp[4 * u + 2] = f2bu(v.z); tmp[4 * u + 3] = f2bu(v.w);
        }
        *(uint4*)(xb + base)     = *(const uint4*)tmp;
        *(uint4*)(xb + base + 8) = *(const uint4*)(tmp + 8);
        return;
    }
    const float* in; u16* out; int K, C, c0, k0;
    if (bid < 108) { in = wqkv;  out = wqkvT;  K = DDIM; C = QKVC;
                     c0 = (bid % 18) * 64; k0 = (bid / 18) * 64; }
    else           { int b2 = bid - 108; in = wproj; out = wprojT; K = DDIM; C = DDIM;
                     c0 = (b2 % 6) * 64; k0 = (b2 / 6) * 64; }
    __shared__ float tr[64][65];
    {
        int kr = t >> 2, cb = (t & 3) * 16;
        const float* gp = in + (size_t)(k0 + kr) * C + c0 + cb;
        #pragma unroll
        for (int u = 0; u < 4; ++u) {
            float4 v = *(const float4*)(gp + 4 * u);
            tr[cb + 4 * u + 0][kr] = v.x;
            tr[cb + 4 * u + 1][kr] = v.y;
            tr[cb + 4 * u + 2][kr] = v.z;
            tr[cb + 4 * u + 3][kr] = v.w;
        }
    }
    __syncthreads();
    {
        int c = t >> 2, kb = (t & 3) * 16;
        __align__(16) u16 tmp[16];
        #pragma unroll
        for (int u = 0; u < 16; ++u) tmp[u] = f2bu(tr[c][kb + u]);
        u16* op = out + (size_t)(c0 + c) * K + k0 + kb;
        *(uint4*)op       = *(const uint4*)tmp;
        *(uint4*)(op + 8) = *(const uint4*)(tmp + 8);
    }
}

// ---------------------------------------------------------------------------
// K1: qkv = xb @ wqkvT, RoPE fused (LDS ping-pong, unchanged from r4).
// Q pre-scaled by 0.125*log2e -> attn exp is exp2(s).
// ---------------------------------------------------------------------------
__global__ __launch_bounds__(256, 4) void qkv_rope_kernel(
    const u16* __restrict__ xb, const u16* __restrict__ wt,
    const float* __restrict__ cs, const float* __restrict__ sn,
    u16* __restrict__ qb, u16* __restrict__ kb, u16* __restrict__ vtb)
{
    __shared__ __align__(16) u16 xs[2][64][68];
    __shared__ __align__(16) u16 ws[2][64][68];
    const int t = threadIdx.x;
    const int wv = t >> 6, lane = t & 63, quad = lane >> 4, lo = lane & 15;
    const int r0 = blockIdx.y * 64;
    const int c0 = blockIdx.x * 64;
    const int sr = t >> 3, sd = (t & 7) * 8;

    st8(&xs[0][sr][sd],      *(const uint4*)(xb + (size_t)(r0 + sr) * DDIM + sd));
    st8(&xs[0][sr + 32][sd], *(const uint4*)(xb + (size_t)(r0 + sr + 32) * DDIM + sd));
    st8(&ws[0][sr][sd],      *(const uint4*)(wt + (size_t)(c0 + sr) * DDIM + sd));
    st8(&ws[0][sr + 32][sd], *(const uint4*)(wt + (size_t)(c0 + sr + 32) * DDIM + sd));
    __syncthreads();

    float4v acc[4] = {};
    for (int kk = 0; kk < 6; ++kk) {
        const int cur = kk & 1, nxt = cur ^ 1;
        const int kkn = (kk < 5 ? kk + 1 : 5) * 64;
        uint4 xp0 = *(const uint4*)(xb + (size_t)(r0 + sr) * DDIM + kkn + sd);
        uint4 xp1 = *(const uint4*)(xb + (size_t)(r0 + sr + 32) * DDIM + kkn + sd);
        uint4 wp0 = *(const uint4*)(wt + (size_t)(c0 + sr) * DDIM + kkn + sd);
        uint4 wp1 = *(const uint4*)(wt + (size_t)(c0 + sr + 32) * DDIM + kkn + sd);

        #pragma unroll
        for (int kf = 0; kf < 2; ++kf) {
            short8v a = ld_frag(&xs[cur][16 * wv + lo][kf * 32 + quad * 8]);
            #pragma unroll
            for (int nt = 0; nt < 4; ++nt) {
                short8v b = ld_frag(&ws[cur][nt * 16 + lo][kf * 32 + quad * 8]);
                acc[nt] = MFMA16(a, b, acc[nt]);
            }
        }
        st8(&xs[nxt][sr][sd], xp0);
        st8(&xs[nxt][sr + 32][sd], xp1);
        st8(&ws[nxt][sr][sd], wp0);
        st8(&ws[nxt][sr + 32][sd], wp1);
        __syncthreads();
    }

    const int sec = blockIdx.x / 6;     // 0=q, 1=k, 2=v
    const int h   = blockIdx.x % 6;
    const int rbase = r0 + 16 * wv + 4 * quad;
    const int bidx  = r0 >> 11;
    const int tbase = rbase & (TT - 1);

    if (sec == 2) {
        #pragma unroll
        for (int nt = 0; nt < 4; ++nt) {
            int d = nt * 16 + lo;
            unsigned a0 = pk2(acc[nt][0], acc[nt][1]);
            unsigned a1 = pk2(acc[nt][2], acc[nt][3]);
            u16* gp = vtb + ((size_t)(bidx * HH + h) * HD + d) * TT + tbase;
            *(uint2*)gp = make_uint2(a0, a1);
        }
    } else {
        u16* dst = (sec == 0) ? qb : kb;
        const float scl = (sec == 0) ? QSCALE : 1.0f;
        #pragma unroll
        for (int np = 0; np < 2; ++np) {
            #pragma unroll
            for (int r = 0; r < 4; ++r) {
                int tpos = tbase + r;
                int ci = np * 16 + lo;
                float cv = cs[tpos * 32 + ci];
                float sv = sn[tpos * 32 + ci];
                float x1 = acc[np][r], x2 = acc[np + 2][r];
                u16* gp = dst + ((size_t)(bidx * HH + h) * TT + tpos) * HD;
                gp[ci]      = f2bu((x1 * cv - x2 * sv) * scl);
                gp[ci + 32] = f2bu((x2 * cv + x1 * sv) * scl);
            }
        }
    }
}

// ---------------------------------------------------------------------------
// K2a: K-SPLIT flash attention (bias==0 fast path; r4 post-mortem: kernel was
// latency-bound with only 3 independent streams/CU due to barrier lockstep).
//  - 4 waves/block each own k-tiles w, w+4..w+28 (softmax is additive over k)
//  - ZERO barriers and ZERO LDS in the main loop; K/V frags load directly
//    from global (L2, XCD-pinned) once per tile, reused across 4 q-groups
//  - private oacc/lacc per wave; 3-barrier LDS tree reduce at the end
// ---------------------------------------------------------------------------
__global__ __launch_bounds__(256, 2) void attn_ksplit_kernel(
    const u16* __restrict__ qb, const u16* __restrict__ kb, const u16* __restrict__ vtb,
    const unsigned* __restrict__ flag, u16* __restrict__ ob)
{
    if (*flag != 0u) return;              // nonzero bias -> fallback kernel

    __shared__ __align__(16) float red_o[2][64][68];  // 34816 B (lane stride 68)
    __shared__ float red_l[4][64];

    const int t = threadIdx.x;
    const int wv = t >> 6, lane = t & 63, quad = lane >> 4, lo = lane & 15;
    const int bh = blockIdx.x;            // bh fastest: XCD = bh % 8
    const int b = bh / HH, h = bh % HH;
    const int q0 = blockIdx.y * 64;

    // Q fragments for all 4 q-groups (B-operand of S^T)
    short8v aq[4][2];
    #pragma unroll
    for (int g = 0; g < 4; ++g) {
        const u16* qp = qb + ((size_t)bh * TT + q0 + g * 16 + lo) * HD + quad * 8;
        aq[g][0] = frag4(*(const uint4*)qp);
        aq[g][1] = frag4(*(const uint4*)(qp + 32));
    }

    const u16* kbase = kb + ((size_t)bh * TT + lo) * HD + quad * 8;
    const u16* vbase = vtb + ((size_t)bh * HD + lo) * TT + quad * 8;

    // first tile (kt = wv) into regs
    uint4 kq[4][2], vq[4][2];
    {
        const size_t ko = (size_t)wv * 64 * HD;
        const size_t vo = (size_t)wv * 64;
        #pragma unroll
        for (int nt = 0; nt < 4; ++nt) {
            kq[nt][0] = *(const uint4*)(kbase + ko + (size_t)nt * 16 * HD);
            kq[nt][1] = *(const uint4*)(kbase + ko + (size_t)nt * 16 * HD + 32);
        }
        #pragma unroll
        for (int dt = 0; dt < 4; ++dt) {
            vq[dt][0] = *(const uint4*)(vbase + (size_t)dt * 16 * TT + vo);
            vq[dt][1] = *(const uint4*)(vbase + (size_t)dt * 16 * TT + vo + 32);
        }
    }

    float4v oacc[4][4] = {};              // [g][dt]: O(q=g*16+4*quad+r, d=dt*16+lo)
    float lacc[4] = {0.f, 0.f, 0.f, 0.f}; // [g]: partial row-sum, q-row = g*16+lo

    for (int j = 0; j < 8; ++j) {
        const int ktn = (j < 7) ? (wv + 4 * (j + 1)) : wv;   // next tile (dummy last)
        const size_t kno = (size_t)ktn * 64 * HD;
        const size_t vno = (size_t)ktn * 64;

        #pragma unroll
        for (int g = 0; g < 4; ++g) {
            // S^T = K Q^T : A = K-frag (m = k-pos), B = Q-frag (n = q-row)
            float4v s[4] = {};
            #pragma unroll
            for (int nt = 0; nt < 4; ++nt)
                s[nt] = MFMA16(frag4(kq[nt][0]), aq[g][0], s[nt]);
            #pragma unroll
            for (int nt = 0; nt < 4; ++nt)
                s[nt] = MFMA16(frag4(kq[nt][1]), aq[g][1], s[nt]);
            if (g == 3) {                  // K consumed: prefetch next tile
                #pragma unroll
                for (int nt = 0; nt < 4; ++nt) {
                    kq[nt][0] = *(const uint4*)(kbase + kno + (size_t)nt * 16 * HD);
                    kq[nt][1] = *(const uint4*)(kbase + kno + (size_t)nt * 16 * HD + 32);
                }
            }

            // p = exp2(s)  (Q pre-scaled; bias==0 on this path)
            unsigned w[8];
            #pragma unroll
            for (int nt = 0; nt < 4; ++nt) {
                float p0 = __builtin_amdgcn_exp2f(s[nt][0]);
                float p1 = __builtin_amdgcn_exp2f(s[nt][1]);
                float p2 = __builtin_amdgcn_exp2f(s[nt][2]);
                float p3 = __builtin_amdgcn_exp2f(s[nt][3]);
                lacc[g] += (p0 + p1) + (p2 + p3);
                w[2 * nt]     = pk2(p0, p1);
                w[2 * nt + 1] = pk2(p2, p3);
            }

            // C-layout (4 k per quad) -> A-layout (8 k per quad), in-register
            pl32swap(w[0], w[2]); pl16swap(w[0], w[2]);
            pl32swap(w[1], w[3]); pl16swap(w[1], w[3]);
            pl32swap(w[4], w[6]); pl16swap(w[4], w[6]);
            pl32swap(w[5], w[7]); pl16swap(w[5], w[7]);
            short8v pa0 = frag4(make_uint4(w[0], w[1], w[2], w[3]));
            short8v pa1 = frag4(make_uint4(w[4], w[5], w[6], w[7]));

            // O += P V  (A = P-frag, B = V^T frag, both in registers)
            #pragma unroll
            for (int dt = 0; dt < 4; ++dt)
                oacc[g][dt] = MFMA16(pa0, frag4(vq[dt][0]), oacc[g][dt]);
            #pragma unroll
            for (int dt = 0; dt < 4; ++dt)
                oacc[g][dt] = MFMA16(pa1, frag4(vq[dt][1]), oacc[g][dt]);
            if (g == 3) {                  // V consumed: prefetch next tile
                #pragma unroll
                for (int dt = 0; dt < 4; ++dt) {
                    vq[dt][0] = *(const uint4*)(vbase + (size_t)dt * 16 * TT + vno);
                    vq[dt][1] = *(const uint4*)(vbase + (size_t)dt * 16 * TT + vno + 32);
                }
            }
        }
    }

    // ---- cross-wave reduce: oacc tree (1&3 -> 0&2 -> 0), l via red_l ----
    #pragma unroll
    for (int g = 0; g < 4; ++g) {
        lacc[g] += __shfl_xor(lacc[g], 16);
        lacc[g] += __shfl_xor(lacc[g], 32);   // all lanes: l(row = g*16+lo), this wave
    }
    if (quad == 0) {
        #pragma unroll
        for (int g = 0; g < 4; ++g) red_l[wv][g * 16 + lo] = lacc[g];
    }
    float* slot0 = &red_o[0][0][0] + (size_t)lane * 68;
    float* slot1 = &red_o[1][0][0] + (size_t)lane * 68;
    if (wv == 1 || wv == 3) {
        float* sp = (wv == 1) ? slot0 : slot1;
        #pragma unroll
        for (int g = 0; g < 4; ++g)
            #pragma unroll
            for (int dt = 0; dt < 4; ++dt)
                *(float4v*)(sp + (g * 4 + dt) * 4) = oacc[g][dt];
    }
    __syncthreads();
    if (wv == 0 || wv == 2) {
        float* sp = (wv == 0) ? slot0 : slot1;
        #pragma unroll
        for (int g = 0; g < 4; ++g)
            #pragma unroll
            for (int dt = 0; dt < 4; ++dt)
                oacc[g][dt] += *(const float4v*)(sp + (g * 4 + dt) * 4);
    }
    __syncthreads();
    if (wv == 2) {
        #pragma unroll
        for (int g = 0; g < 4; ++g)
            #pragma unroll
            for (int dt = 0; dt < 4; ++dt)
                *(float4v*)(slot1 + (g * 4 + dt) * 4) = oacc[g][dt];
    }
    __syncthreads();
    if (wv == 0) {
        #pragma unroll
        for (int g = 0; g < 4; ++g) {
            #pragma unroll
            for (int dt = 0; dt < 4; ++dt)
                oacc[g][dt] += *(const float4v*)(slot1 + (g * 4 + dt) * 4);
            float lt = red_l[0][g * 16 + lo] + red_l[1][g * 16 + lo]
                     + red_l[2][g * 16 + lo] + red_l[3][g * 16 + lo];
            #pragma unroll
            for (int r = 0; r < 4; ++r) {
                float lr = __shfl(lt, 4 * quad + r);
                float inv = 1.f / lr;
                u16* gp = ob + ((size_t)b * TT + q0 + g * 16 + 4 * quad + r) * DDIM
                             + h * HD + lo;
                #pragma unroll
                for (int dt = 0; dt < 4; ++dt)
                    gp[dt * 16] = f2bu(oacc[g][dt][r] * inv);
            }
        }
    }
}

// ---------------------------------------------------------------------------
// K2b: bias-nonzero fallback (r4's proven LDS-staged loop, f32 bias).
// Early-exits when flag==0.
// ---------------------------------------------------------------------------
__global__ __launch_bounds__(256, 4) void attn_bias_kernel(
    const u16* __restrict__ qb, const u16* __restrict__ kb, const u16* __restrict__ vtb,
    const float* __restrict__ bias, const unsigned* __restrict__ flag,
    u16* __restrict__ ob)
{
    if (*flag == 0u) return;

    __shared__ __align__(16) u16 ks[2][64][68];
    __shared__ __align__(16) u16 vt[2][64][68];

    const int t = threadIdx.x;
    const int wv = t >> 6, lane = t & 63, quad = lane >> 4, lo = lane & 15;
    const int bh = blockIdx.x;
    const int b = bh / HH, h = bh % HH;
    const int q0 = blockIdx.y * 64;
    const int qrow = q0 + 16 * wv + lo;

    const u16* qbase = qb + ((size_t)bh * TT + qrow) * HD + quad * 8;
    short8v aq0 = frag4(*(const uint4*)qbase);
    short8v aq1 = frag4(*(const uint4*)(qbase + 32));

    const int sr = t >> 3, sd = (t & 7) * 8;
    const u16* kbbase = kb + (size_t)bh * TT * HD;
    const u16* vtbase = vtb + (size_t)bh * HD * TT;
    const float* brow = bias + (size_t)qrow * TT + 4 * quad;

    st8(&ks[0][sr][sd],      *(const uint4*)(kbbase + (size_t)sr * HD + sd));
    st8(&ks[0][sr + 32][sd], *(const uint4*)(kbbase + (size_t)(sr + 32) * HD + sd));
    st8(&vt[0][sr][sd],      *(const uint4*)(vtbase + (size_t)sr * TT + sd));
    st8(&vt[0][sr + 32][sd], *(const uint4*)(vtbase + (size_t)(sr + 32) * TT + sd));
    float4 bcur[4];
    #pragma unroll
    for (int nt = 0; nt < 4; ++nt) bcur[nt] = *(const float4*)(brow + nt * 16);
    __syncthreads();

    float4v oacc[4] = {};
    float lacc[4] = {0.f, 0.f, 0.f, 0.f};

    for (int kt = 0; kt < TT / 64; ++kt) {
        const int cur = kt & 1, nxt = cur ^ 1;
        const int kn = (kt < 31 ? kt + 1 : 31) * 64;

        uint4 kp0 = *(const uint4*)(kbbase + (size_t)(kn + sr) * HD + sd);
        uint4 kp1 = *(const uint4*)(kbbase + (size_t)(kn + sr + 32) * HD + sd);
        uint4 vp0 = *(const uint4*)(vtbase + (size_t)sr * TT + kn + sd);
        uint4 vp1 = *(const uint4*)(vtbase + (size_t)(sr + 32) * TT + kn + sd);
        float4 bnxt[4];
        #pragma unroll
        for (int nt = 0; nt < 4; ++nt) bnxt[nt] = *(const float4*)(brow + kn + nt * 16);

        float4v s[4] = {};
        #pragma unroll
        for (int kf = 0; kf < 2; ++kf) {
            #pragma unroll
            for (int nt = 0; nt < 4; ++nt) {
                short8v kfr = ld_frag(&ks[cur][nt * 16 + lo][kf * 32 + quad * 8]);
                s[nt] = MFMA16(kfr, (kf ? aq1 : aq0), s[nt]);
            }
        }

        unsigned w[8];
        #pragma unroll
        for (int nt = 0; nt < 4; ++nt) {
            float p0 = __builtin_amdgcn_exp2f(fmaf(bcur[nt].x, LOG2E, s[nt][0]));
            float p1 = __builtin_amdgcn_exp2f(fmaf(bcur[nt].y, LOG2E, s[nt][1]));
            float p2 = __builtin_amdgcn_exp2f(fmaf(bcur[nt].z, LOG2E, s[nt][2]));
            float p3 = __builtin_amdgcn_exp2f(fmaf(bcur[nt].w, LOG2E, s[nt][3]));
            lacc[nt] += (p0 + p1) + (p2 + p3);
            w[2 * nt]     = pk2(p0, p1);
            w[2 * nt + 1] = pk2(p2, p3);
        }

        pl32swap(w[0], w[2]); pl16swap(w[0], w[2]);
        pl32swap(w[1], w[3]); pl16swap(w[1], w[3]);
        pl32swap(w[4], w[6]); pl16swap(w[4], w[6]);
        pl32swap(w[5], w[7]); pl16swap(w[5], w[7]);
        short8v pa0 = frag4(make_uint4(w[0], w[1], w[2], w[3]));
        short8v pa1 = frag4(make_uint4(w[4], w[5], w[6], w[7]));

        #pragma unroll
        for (int kf = 0; kf < 2; ++kf) {
            #pragma unroll
            for (int dt = 0; dt < 4; ++dt) {
                short8v bv = ld_frag(&vt[cur][dt * 16 + lo][kf * 32 + quad * 8]);
                oacc[dt] = MFMA16((kf ? pa1 : pa0), bv, oacc[dt]);
            }
        }

        st8(&ks[nxt][sr][sd], kp0);
        st8(&ks[nxt][sr + 32][sd], kp1);
        st8(&vt[nxt][sr][sd], vp0);
        st8(&vt[nxt][sr + 32][sd], vp1);
        #pragma unroll
        for (int nt = 0; nt < 4; ++nt) bcur[nt] = bnxt[nt];
        __syncthreads();
    }

    float l = (lacc[0] + lacc[1]) + (lacc[2] + lacc[3]);
    l += __shfl_xor(l, 16);
    l += __shfl_xor(l, 32);
    #pragma unroll
    for (int r = 0; r < 4; ++r) {
        float lr = __shfl(l, 4 * quad + r);
        float inv = 1.f / lr;
        u16* gp = ob + ((size_t)b * TT + q0 + 16 * wv + 4 * quad + r) * DDIM + h * HD + lo;
        #pragma unroll
        for (int dt = 0; dt < 4; ++dt)
            gp[dt * 16] = f2bu(oacc[dt][r] * inv);
    }
}

// ---------------------------------------------------------------------------
// K3: out = O @ w_proj (MFMA), f32 output. Ping-pong (unchanged from r4).
// ---------------------------------------------------------------------------
__global__ __launch_bounds__(256, 4) void proj_kernel(
    const u16* __restrict__ o, const u16* __restrict__ wt, float* __restrict__ out)
{
    __shared__ __align__(16) u16 os[2][64][68];
    __shared__ __align__(16) u16 ws[2][64][68];
    const int t = threadIdx.x;
    const int wv = t >> 6, lane = t & 63, quad = lane >> 4, lo = lane & 15;
    const int r0 = blockIdx.y * 64, c0 = blockIdx.x * 64;
    const int sr = t >> 3, sd = (t & 7) * 8;

    st8(&os[0][sr][sd],      *(const uint4*)(o + (size_t)(r0 + sr) * DDIM + sd));
    st8(&os[0][sr + 32][sd], *(const uint4*)(o + (size_t)(r0 + sr + 32) * DDIM + sd));
    st8(&ws[0][sr][sd],      *(const uint4*)(wt + (size_t)(c0 + sr) * DDIM + sd));
    st8(&ws[0][sr + 32][sd], *(const uint4*)(wt + (size_t)(c0 + sr + 32) * DDIM + sd));
    __syncthreads();

    float4v acc[4] = {};
    for (int kk = 0; kk < 6; ++kk) {
        const int cur = kk & 1, nxt = cur ^ 1;
        const int kkn = (kk < 5 ? kk + 1 : 5) * 64;
        uint4 op0 = *(const uint4*)(o + (size_t)(r0 + sr) * DDIM + kkn + sd);
        uint4 op1 = *(const uint4*)(o + (size_t)(r0 + sr + 32) * DDIM + kkn + sd);
        uint4 wp0 = *(const uint4*)(wt + (size_t)(c0 + sr) * DDIM + kkn + sd);
        uint4 wp1 = *(const uint4*)(wt + (size_t)(c0 + sr + 32) * DDIM + kkn + sd);

        #pragma unroll
        for (int kf = 0; kf < 2; ++kf) {
            short8v a = ld_frag(&os[cur][16 * wv + lo][kf * 32 + quad * 8]);
            #pragma unroll
            for (int nt = 0; nt < 4; ++nt) {
                short8v bfr = ld_frag(&ws[cur][nt * 16 + lo][kf * 32 + quad * 8]);
                acc[nt] = MFMA16(a, bfr, acc[nt]);
            }
        }
        st8(&os[nxt][sr][sd], op0);
        st8(&os[nxt][sr + 32][sd], op1);
        st8(&ws[nxt][sr][sd], wp0);
        st8(&ws[nxt][sr + 32][sd], wp1);
        __syncthreads();
    }
    #pragma unroll
    for (int r = 0; r < 4; ++r) {
        float* gp = out + (size_t)(r0 + 16 * wv + 4 * quad + r) * DDIM + c0;
        #pragma unroll
        for (int nt = 0; nt < 4; ++nt)
            gp[nt * 16 + lo] = acc[nt][r];
    }
}

extern "C" void kernel_launch(void* const* d_in, const int* in_sizes, int n_in,
                              void* d_out, int out_size, void* d_ws, size_t ws_size,
                              hipStream_t stream) {
    const float* x     = (const float*)d_in[0];
    const float* bias  = (const float*)d_in[1];
    const float* cs    = (const float*)d_in[2];
    const float* sn    = (const float*)d_in[3];
    const float* wqkv  = (const float*)d_in[4];
    const float* wproj = (const float*)d_in[5];
    float* out = (float*)d_out;

    u16* wqkvT  = (u16*)d_ws;                         // [1152][384]
    u16* wprojT = wqkvT + (size_t)QKVC * DDIM;        // [384][384]
    u16* qb     = wprojT + (size_t)DDIM * DDIM;       // [bh][t][d]
    u16* kb     = qb + (size_t)BB * HH * TT * HD;     // [bh][t][d]
    u16* vtb    = kb + (size_t)BB * HH * TT * HD;     // [bh][d][t]
    u16* ob     = vtb + (size_t)BB * HH * TT * HD;    // [b][t][h*64+d]
    u16* xb     = ob + (size_t)BT * DDIM;             // [b*t][384] bf16 x
    unsigned* flag = (unsigned*)(xb + (size_t)BT * DDIM);

    hipMemsetAsync(flag, 0, sizeof(unsigned), stream);
    prep_kernel<<<dim3(144 + BT * DDIM / 4096 + TT * TT / 4096), 256, 0, stream>>>(
        wqkv, wproj, x, bias, wqkvT, wprojT, xb, flag);
    qkv_rope_kernel<<<dim3(QKVC / 64, BT / 64), 256, 0, stream>>>(
        xb, wqkvT, cs, sn, qb, kb, vtb);
    attn_ksplit_kernel<<<dim3(BB * HH, TT / 64), 256, 0, stream>>>(
        qb, kb, vtb, flag, ob);
    attn_bias_kernel<<<dim3(BB * HH, TT / 64), 256, 0, stream>>>(
        qb, kb, vtb, bias, flag, ob);
    proj_kernel<<<dim3(DDIM / 64, BT / 64), 256, 0, stream>>>(ob, wprojT, out);
}